// Round 3
// baseline (906.569 us; speedup 1.0000x reference)
//
#include <hip/hip_runtime.h>
#include <hip/hip_bf16.h>

#define NN 50000
#define NE 400000
#define DIN 128
#define DH 32
#define NH 10
#define HID 320
#define DOUT 32
#define NEG_SLOPE 0.2f
#define EPS_BN 1e-5f

// ---------------- GEMM1: x[NN,128] @ {Wl,Wr}[128,320] + b -> xl1, xr1 ----------------
__global__ __launch_bounds__(256) void gemm1_kernel(
    const float* __restrict__ x,
    const float* __restrict__ Wl, const float* __restrict__ bl,
    const float* __restrict__ Wr, const float* __restrict__ br,
    float* __restrict__ xl1, float* __restrict__ xr1)
{
    __shared__ float xs[32][132];   // +4 pad: banks (tr*4 + k) distinct
    __shared__ float wls[128][32];
    __shared__ float wrs[128][32];
    const int tid = threadIdx.x;
    const int r0 = blockIdx.x * 32;
    const int c0 = blockIdx.y * 32;

    // x tile: 32 rows x 128 = 1024 float4
    for (int i = tid; i < 1024; i += 256) {
        int row = i >> 5;
        int cc  = (i & 31) << 2;
        float4 v = make_float4(0.f, 0.f, 0.f, 0.f);
        if (r0 + row < NN)
            v = *(const float4*)(x + (size_t)(r0 + row) * DIN + cc);
        *(float4*)&xs[row][cc] = v;
    }
    // W tiles: 128 x 32 = 1024 float4 total each
    for (int i = tid; i < 1024; i += 256) {
        int kr = i >> 3;
        int cc = (i & 7) << 2;
        *(float4*)&wls[kr][cc] = *(const float4*)(Wl + (size_t)kr * HID + c0 + cc);
        *(float4*)&wrs[kr][cc] = *(const float4*)(Wr + (size_t)kr * HID + c0 + cc);
    }
    __syncthreads();

    const int tr  = tid >> 4;          // 0..15 -> rows tr, tr+16
    const int tcc = (tid & 15) << 1;   // 0..30 step 2
    float aL00=0,aL01=0,aL10=0,aL11=0,aR00=0,aR01=0,aR10=0,aR11=0;
    #pragma unroll 4
    for (int k = 0; k < 128; ++k) {
        float xa = xs[tr][k];
        float xb = xs[tr + 16][k];
        float2 wl = *(float2*)&wls[k][tcc];
        float2 wr = *(float2*)&wrs[k][tcc];
        aL00 = fmaf(xa, wl.x, aL00); aL01 = fmaf(xa, wl.y, aL01);
        aL10 = fmaf(xb, wl.x, aL10); aL11 = fmaf(xb, wl.y, aL11);
        aR00 = fmaf(xa, wr.x, aR00); aR01 = fmaf(xa, wr.y, aR01);
        aR10 = fmaf(xb, wr.x, aR10); aR11 = fmaf(xb, wr.y, aR11);
    }
    const int gc = c0 + tcc;
    const float2 blv = *(const float2*)(bl + gc);
    const float2 brv = *(const float2*)(br + gc);
    const int r1 = r0 + tr, r2 = r1 + 16;
    if (r1 < NN) {
        float2 o; o.x = aL00 + blv.x; o.y = aL01 + blv.y;
        *(float2*)(xl1 + (size_t)r1 * HID + gc) = o;
        o.x = aR00 + brv.x; o.y = aR01 + brv.y;
        *(float2*)(xr1 + (size_t)r1 * HID + gc) = o;
    }
    if (r2 < NN) {
        float2 o; o.x = aL10 + blv.x; o.y = aL11 + blv.y;
        *(float2*)(xl1 + (size_t)r2 * HID + gc) = o;
        o.x = aR10 + brv.x; o.y = aR11 + brv.y;
        *(float2*)(xr1 + (size_t)r2 * HID + gc) = o;
    }
}

// ---------------- CSR build ----------------
__global__ void hist_kernel(const int* __restrict__ dst, int* __restrict__ deg) {
    int e = blockIdx.x * blockDim.x + threadIdx.x;
    if (e < NE) atomicAdd(&deg[dst[e]], 1);
}

__global__ __launch_bounds__(1024) void scan_kernel(const int* __restrict__ deg,
        int* __restrict__ row_ptr, int* __restrict__ cursor) {
    __shared__ int sums[1024];
    const int tid = threadIdx.x;
    const int CH = (NN + 1023) / 1024;  // 49
    const int st = tid * CH;
    const int en = min(st + CH, NN);
    int s = 0;
    for (int i = st; i < en; ++i) s += deg[i];
    sums[tid] = s;
    __syncthreads();
    for (int off = 1; off < 1024; off <<= 1) {
        int v = (tid >= off) ? sums[tid - off] : 0;
        __syncthreads();
        sums[tid] += v;
        __syncthreads();
    }
    int run = (tid == 0) ? 0 : sums[tid - 1];
    for (int i = st; i < en; ++i) {
        row_ptr[i] = run; cursor[i] = run; run += deg[i];
    }
    if (tid == 1023) row_ptr[NN] = sums[1023];
}

__global__ void scatter_kernel(const int* __restrict__ src, const int* __restrict__ dst,
        int* __restrict__ cursor, int* __restrict__ sorted_src) {
    int e = blockIdx.x * blockDim.x + threadIdx.x;
    if (e < NE) {
        int d = dst[e];
        int p = atomicAdd(&cursor[d], 1);
        sorted_src[p] = src[e];
    }
}

// ---------------- Layer-1 aggregation: online segment softmax, block = node ----------------
__global__ __launch_bounds__(320) void agg1_kernel(
    const float* __restrict__ xl1, const float* __restrict__ xr1,
    const int* __restrict__ row_ptr, const int* __restrict__ sorted_src,
    const float* __restrict__ att1, const float* __restrict__ bias1,
    float* __restrict__ h1)
{
    const int n = blockIdx.x;
    const int tid = threadIdx.x;              // tid = h*32 + c
    const float attv = att1[tid];
    const float xrd  = xr1[(size_t)n * HID + tid];
    const int rp = row_ptr[n];
    const int deg = row_ptr[n + 1] - rp;
    float m = -1e30f, l = 0.f, acc = 0.f;
    for (int i = 0; i < deg; ++i) {
        int s = sorted_src[rp + i];
        float xls = xl1[(size_t)s * HID + tid];
        float e = xls + xrd;
        e = (e >= 0.f) ? e : NEG_SLOPE * e;
        float v = e * attv;
        v += __shfl_xor(v, 16);
        v += __shfl_xor(v, 8);
        v += __shfl_xor(v, 4);
        v += __shfl_xor(v, 2);
        v += __shfl_xor(v, 1);               // per-head score, replicated in 32-group
        float mn = fmaxf(m, v);
        float corr = __expf(m - mn);
        float p = __expf(v - mn);
        l = l * corr + p;
        acc = acc * corr + p * xls;
        m = mn;
    }
    h1[(size_t)n * HID + tid] = acc / (l + 1e-16f) + bias1[tid];
}

// ---------------- BatchNorm stats / finalize / apply+PReLU ----------------
__global__ __launch_bounds__(320) void bnstats_kernel(const float* __restrict__ h1,
        double* __restrict__ bn_sum, double* __restrict__ bn_sq) {
    const int tid = threadIdx.x;
    double s = 0.0, q = 0.0;
    for (int n = blockIdx.x; n < NN; n += gridDim.x) {
        float v = h1[(size_t)n * HID + tid];
        s += v; q += (double)v * v;
    }
    atomicAdd(&bn_sum[tid], s);
    atomicAdd(&bn_sq[tid], q);
}

__global__ void bnfinal_kernel(const double* __restrict__ bn_sum, const double* __restrict__ bn_sq,
        const float* __restrict__ gamma, const float* __restrict__ beta,
        float* __restrict__ scale, float* __restrict__ shift) {
    int c = threadIdx.x;
    double mean = bn_sum[c] / (double)NN;
    double var  = bn_sq[c] / (double)NN - mean * mean;
    float sc = gamma[c] * rsqrtf((float)var + EPS_BN);
    scale[c] = sc;
    shift[c] = beta[c] - (float)mean * sc;
}

__global__ __launch_bounds__(320) void bnapply_kernel(float* __restrict__ h,
        const float* __restrict__ scale, const float* __restrict__ shift,
        const float* __restrict__ prelu_a) {
    const int tid = threadIdx.x;
    const float sc = scale[tid], sh = shift[tid], a = prelu_a[0];
    for (int n = blockIdx.x; n < NN; n += gridDim.x) {
        size_t idx = (size_t)n * HID + tid;
        float y = h[idx] * sc + sh;
        h[idx] = (y >= 0.f) ? y : a * y;
    }
}

// ---------------- GEMM2: h[NN,320] @ {Wl2,Wr2}[320,32] + b -> xl2, xr2 ----------------
__global__ __launch_bounds__(256) void gemm2_kernel(const float* __restrict__ h,
        const float* __restrict__ Wl2, const float* __restrict__ bl2,
        const float* __restrict__ Wr2, const float* __restrict__ br2,
        float* __restrict__ xl2, float* __restrict__ xr2)
{
    const int tid = threadIdx.x;
    const int r = blockIdx.x * 8 + (tid >> 5);
    const int c = tid & 31;
    if (r >= NN) return;
    const float* hrow = h + (size_t)r * HID;
    float aL = bl2[c], aR = br2[c];
    #pragma unroll 8
    for (int k = 0; k < HID; ++k) {
        float hv = hrow[k];
        aL = fmaf(hv, Wl2[k * DOUT + c], aL);
        aR = fmaf(hv, Wr2[k * DOUT + c], aR);
    }
    xl2[(size_t)r * DOUT + c] = aL;
    xr2[(size_t)r * DOUT + c] = aR;
}

// ---------------- Layer-2 aggregation + bias + log_softmax, wave = node ----------------
__global__ __launch_bounds__(64) void agg2_kernel(
    const float* __restrict__ xl2, const float* __restrict__ xr2,
    const int* __restrict__ row_ptr, const int* __restrict__ sorted_src,
    const float* __restrict__ att2, const float* __restrict__ bias2,
    float* __restrict__ out)
{
    const int n = blockIdx.x;
    const int c = threadIdx.x & 31;   // lanes 32..63 duplicate 0..31
    const float attv = att2[c];
    const float xrd = xr2[(size_t)n * DOUT + c];
    const int rp = row_ptr[n];
    const int deg = row_ptr[n + 1] - rp;
    float m = -1e30f, l = 0.f, acc = 0.f;
    for (int i = 0; i < deg; ++i) {
        int s = sorted_src[rp + i];
        float xls = xl2[(size_t)s * DOUT + c];
        float e = xls + xrd;
        e = (e >= 0.f) ? e : NEG_SLOPE * e;
        float v = e * attv;
        v += __shfl_xor(v, 16);
        v += __shfl_xor(v, 8);
        v += __shfl_xor(v, 4);
        v += __shfl_xor(v, 2);
        v += __shfl_xor(v, 1);
        float mn = fmaxf(m, v);
        float corr = __expf(m - mn);
        float p = __expf(v - mn);
        l = l * corr + p;
        acc = acc * corr + p * xls;
        m = mn;
    }
    float o = acc / (l + 1e-16f) + bias2[c];
    // log_softmax over the 32 channels
    float mx = o;
    mx = fmaxf(mx, __shfl_xor(mx, 16));
    mx = fmaxf(mx, __shfl_xor(mx, 8));
    mx = fmaxf(mx, __shfl_xor(mx, 4));
    mx = fmaxf(mx, __shfl_xor(mx, 2));
    mx = fmaxf(mx, __shfl_xor(mx, 1));
    float pe = __expf(o - mx);
    float se = pe;
    se += __shfl_xor(se, 16);
    se += __shfl_xor(se, 8);
    se += __shfl_xor(se, 4);
    se += __shfl_xor(se, 2);
    se += __shfl_xor(se, 1);
    float lsm = o - mx - logf(se);
    if (threadIdx.x < 32) {
        out[(size_t)n * DOUT + c] = o;                 // output 0
        out[(size_t)(NN + n) * DOUT + c] = lsm;        // output 1 (log_softmax)
    }
}

extern "C" void kernel_launch(void* const* d_in, const int* in_sizes, int n_in,
                              void* d_out, int out_size, void* d_ws, size_t ws_size,
                              hipStream_t stream)
{
    const float* x       = (const float*)d_in[0];
    const int*   ei      = (const int*)d_in[1];
    const float* Wl1     = (const float*)d_in[2];
    const float* bl1     = (const float*)d_in[3];
    const float* Wr1     = (const float*)d_in[4];
    const float* br1     = (const float*)d_in[5];
    const float* att1    = (const float*)d_in[6];
    const float* bias1   = (const float*)d_in[7];
    const float* gamma   = (const float*)d_in[8];
    const float* beta    = (const float*)d_in[9];
    const float* prelu_a = (const float*)d_in[10];
    const float* Wl2     = (const float*)d_in[11];
    const float* bl2     = (const float*)d_in[12];
    const float* Wr2     = (const float*)d_in[13];
    const float* br2     = (const float*)d_in[14];
    const float* att2    = (const float*)d_in[15];
    const float* bias2   = (const float*)d_in[16];
    const int* src = ei;
    const int* dst = ei + NE;

    // workspace layout (~194.2 MB)
    char* w = (char*)d_ws;
    float* xl1 = (float*)w;                       // NN*HID
    float* xr1 = xl1 + (size_t)NN * HID;          // NN*HID
    float* h1  = xr1 + (size_t)NN * HID;          // NN*HID (in-place -> h2)
    char* small = (char*)(h1 + (size_t)NN * HID); // byte offset 192,000,000 (8-aligned)
    double* bn_sum = (double*)small;              // HID
    double* bn_sq  = bn_sum + HID;                // HID
    float* scale   = (float*)(bn_sq + HID);       // HID
    float* shift   = scale + HID;                 // HID
    int* deg       = (int*)(shift + HID);         // NN
    int* cursor    = deg + NN;                    // NN
    int* sorted    = cursor + NN;                 // NE
    int* row_ptr   = sorted + NE;                 // NN+1
    // layer-2 buffers reuse the (dead) xl1 region
    float* xl2 = xl1;                             // NN*DOUT
    float* xr2 = xl1 + (size_t)NN * DOUT;         // NN*DOUT

    hipMemsetAsync(deg, 0, NN * sizeof(int), stream);
    hipMemsetAsync(bn_sum, 0, 2 * HID * sizeof(double), stream);

    gemm1_kernel<<<dim3((NN + 31) / 32, HID / 32), 256, 0, stream>>>(
        x, Wl1, bl1, Wr1, br1, xl1, xr1);
    hist_kernel<<<(NE + 255) / 256, 256, 0, stream>>>(dst, deg);
    scan_kernel<<<1, 1024, 0, stream>>>(deg, row_ptr, cursor);
    scatter_kernel<<<(NE + 255) / 256, 256, 0, stream>>>(src, dst, cursor, sorted);
    agg1_kernel<<<NN, HID, 0, stream>>>(xl1, xr1, row_ptr, sorted, att1, bias1, h1);
    bnstats_kernel<<<512, HID, 0, stream>>>(h1, bn_sum, bn_sq);
    bnfinal_kernel<<<1, HID, 0, stream>>>(bn_sum, bn_sq, gamma, beta, scale, shift);
    bnapply_kernel<<<2048, HID, 0, stream>>>(h1, scale, shift, prelu_a);
    gemm2_kernel<<<(NN + 7) / 8, 256, 0, stream>>>(h1, Wl2, bl2, Wr2, br2, xl2, xr2);
    agg2_kernel<<<NN, 64, 0, stream>>>(xl2, xr2, row_ptr, sorted, att2, bias2, (float*)d_out);
}

// Round 4
// 636.574 us; speedup vs baseline: 1.4241x; 1.4241x over previous
//
#include <hip/hip_runtime.h>
#include <hip/hip_bf16.h>

#define NN 50000
#define NE 400000
#define DIN 128
#define DH 32
#define NH 10
#define HID 320
#define DOUT 32
#define NEG_SLOPE 0.2f
#define EPS_BN 1e-5f

typedef __attribute__((ext_vector_type(8))) short short8;
typedef __attribute__((ext_vector_type(4))) float f32x4;

// f32 -> bf16 with round-to-nearest-even (values are finite; no NaN handling)
__device__ inline unsigned short f2bf(float f) {
    unsigned int u = __float_as_uint(f);
    u += 0x7fffu + ((u >> 16) & 1u);
    return (unsigned short)(u >> 16);
}
__device__ inline float bf2f(unsigned short u) {
    return __uint_as_float(((unsigned int)u) << 16);
}

// ---------------- GEMM1 (MFMA bf16): x[NN,128] @ {Wl,Wr}[128,320] + b -> bf16 xl1, xr1 ----
// grid (10, 782): blockIdx.x = col-tile (fastest; consecutive blocks share the x-tile in L2)
__global__ __launch_bounds__(256) void gemm1_kernel(
    const float* __restrict__ x,
    const float* __restrict__ Wl, const float* __restrict__ bl,
    const float* __restrict__ Wr, const float* __restrict__ br,
    unsigned short* __restrict__ xl1, unsigned short* __restrict__ xr1)
{
    __shared__ short xs[64 * 128];      // bf16 bits, XOR-swizzled 16B units (T2)
    __shared__ short wt[2][32 * 136];   // W^T per matrix: [col][k], k-stride 136 (pad)
    const int tid = threadIdx.x;
    const int c0 = blockIdx.x * 32;
    const int r0 = blockIdx.y * 64;

    // stage x tile: 64 rows x 128 (2048 float4)
    for (int ch = tid; ch < 2048; ch += 256) {
        int rr = ch >> 5, c4 = (ch & 31) << 2;
        float4 v = make_float4(0.f, 0.f, 0.f, 0.f);
        if (r0 + rr < NN) v = *(const float4*)(x + (size_t)(r0 + rr) * DIN + c4);
        short4 s;
        s.x = (short)f2bf(v.x); s.y = (short)f2bf(v.y);
        s.z = (short)f2bf(v.z); s.w = (short)f2bf(v.w);
        int u = (rr * 128 + c4) ^ ((rr & 7) << 3);   // swizzle 16B units within 8-row stripe
        *(short4*)&xs[u] = s;
    }
    // stage W tiles transposed: wt[mat][c][k]
    for (int f = tid; f < 2048; f += 256) {
        int mat = f >> 10, fi = f & 1023;
        int k = fi >> 3, cq = (fi & 7) << 2;
        const float* Wp = mat ? Wr : Wl;
        float4 v = *(const float4*)(Wp + (size_t)k * HID + c0 + cq);
        short* dp = &wt[mat][0];
        dp[(cq + 0) * 136 + k] = (short)f2bf(v.x);
        dp[(cq + 1) * 136 + k] = (short)f2bf(v.y);
        dp[(cq + 2) * 136 + k] = (short)f2bf(v.z);
        dp[(cq + 3) * 136 + k] = (short)f2bf(v.w);
    }
    __syncthreads();

    const int w = tid >> 6, lane = tid & 63;
    const int arow = w * 16 + (lane & 15);
    const int kgrp = (lane >> 4) << 3;               // 0,8,16,24
    f32x4 acc00 = {}, acc01 = {}, acc10 = {}, acc11 = {};
    #pragma unroll
    for (int kk = 0; kk < 4; ++kk) {
        int au = (arow * 128 + kk * 32 + kgrp) ^ ((arow & 7) << 3);
        short8 a = *(short8*)&xs[au];
        int bu0 = (lane & 15) * 136 + kk * 32 + kgrp;
        int bu1 = (16 + (lane & 15)) * 136 + kk * 32 + kgrp;
        short8 bL0 = *(short8*)&wt[0][bu0];
        short8 bL1 = *(short8*)&wt[0][bu1];
        short8 bR0 = *(short8*)&wt[1][bu0];
        short8 bR1 = *(short8*)&wt[1][bu1];
        acc00 = __builtin_amdgcn_mfma_f32_16x16x32_bf16(a, bL0, acc00, 0, 0, 0);
        acc01 = __builtin_amdgcn_mfma_f32_16x16x32_bf16(a, bL1, acc01, 0, 0, 0);
        acc10 = __builtin_amdgcn_mfma_f32_16x16x32_bf16(a, bR0, acc10, 0, 0, 0);
        acc11 = __builtin_amdgcn_mfma_f32_16x16x32_bf16(a, bR1, acc11, 0, 0, 0);
    }
    // epilogue: C/D layout col=lane&15, row=(lane>>4)*4+reg  [m89]
    const int orow = r0 + w * 16 + ((lane >> 4) << 2);
    #pragma unroll
    for (int cf = 0; cf < 2; ++cf) {
        const int col = c0 + cf * 16 + (lane & 15);
        const float blv = bl[col], brv = br[col];
        const f32x4 aL = cf ? acc01 : acc00;
        const f32x4 aR = cf ? acc11 : acc10;
        #pragma unroll
        for (int reg = 0; reg < 4; ++reg) {
            int row = orow + reg;
            if (row < NN) {
                xl1[(size_t)row * HID + col] = f2bf(aL[reg] + blv);
                xr1[(size_t)row * HID + col] = f2bf(aR[reg] + brv);
            }
        }
    }
}

// ---------------- CSR build ----------------
__global__ void hist_kernel(const int* __restrict__ dst, int* __restrict__ deg) {
    int e = blockIdx.x * blockDim.x + threadIdx.x;
    if (e < NE) atomicAdd(&deg[dst[e]], 1);
}

__global__ __launch_bounds__(1024) void scan_kernel(const int* __restrict__ deg,
        int* __restrict__ row_ptr, int* __restrict__ cursor) {
    __shared__ int sums[1024];
    const int tid = threadIdx.x;
    const int CH = (NN + 1023) / 1024;  // 49
    const int st = tid * CH;
    const int en = min(st + CH, NN);
    int s = 0;
    for (int i = st; i < en; ++i) s += deg[i];
    sums[tid] = s;
    __syncthreads();
    for (int off = 1; off < 1024; off <<= 1) {
        int v = (tid >= off) ? sums[tid - off] : 0;
        __syncthreads();
        sums[tid] += v;
        __syncthreads();
    }
    int run = (tid == 0) ? 0 : sums[tid - 1];
    for (int i = st; i < en; ++i) {
        row_ptr[i] = run; cursor[i] = run; run += deg[i];
    }
    if (tid == 1023) row_ptr[NN] = sums[1023];
}

__global__ void scatter_kernel(const int* __restrict__ src, const int* __restrict__ dst,
        int* __restrict__ cursor, int* __restrict__ sorted_src) {
    int e = blockIdx.x * blockDim.x + threadIdx.x;
    if (e < NE) {
        int d = dst[e];
        int p = atomicAdd(&cursor[d], 1);
        sorted_src[p] = src[e];
    }
}

// ---------------- Layer-1 aggregation: LDS index prefetch + 2-way ILP online softmax ------
__global__ __launch_bounds__(320) void agg1_kernel(
    const unsigned short* __restrict__ xl1, const unsigned short* __restrict__ xr1,
    const int* __restrict__ row_ptr, const int* __restrict__ sorted_src,
    const float* __restrict__ att1, const float* __restrict__ bias1,
    float* __restrict__ h1)
{
    __shared__ int sidx[64];
    const int n = blockIdx.x;
    const int tid = threadIdx.x;              // tid = h*32 + c
    const float attv = att1[tid];
    const float xrd  = bf2f(xr1[(size_t)n * HID + tid]);
    const int rp = row_ptr[n];
    const int deg = row_ptr[n + 1] - rp;
    float m0 = -1e30f, l0 = 0.f, a0 = 0.f;
    float m1 = -1e30f, l1 = 0.f, a1 = 0.f;
    for (int base = 0; base < deg; base += 64) {
        int cnt = min(64, deg - base);
        __syncthreads();
        if (tid < cnt) sidx[tid] = sorted_src[rp + base + tid];
        __syncthreads();
        int i = 0;
        for (; i + 1 < cnt; i += 2) {
            int s0 = sidx[i], s1 = sidx[i + 1];
            float x0 = bf2f(xl1[(size_t)s0 * HID + tid]);
            float x1 = bf2f(xl1[(size_t)s1 * HID + tid]);
            float e0 = x0 + xrd; e0 = (e0 >= 0.f) ? e0 : NEG_SLOPE * e0;
            float e1 = x1 + xrd; e1 = (e1 >= 0.f) ? e1 : NEG_SLOPE * e1;
            float v0 = e0 * attv, v1 = e1 * attv;
            v0 += __shfl_xor(v0, 16); v1 += __shfl_xor(v1, 16);
            v0 += __shfl_xor(v0, 8);  v1 += __shfl_xor(v1, 8);
            v0 += __shfl_xor(v0, 4);  v1 += __shfl_xor(v1, 4);
            v0 += __shfl_xor(v0, 2);  v1 += __shfl_xor(v1, 2);
            v0 += __shfl_xor(v0, 1);  v1 += __shfl_xor(v1, 1);
            float mn0 = fmaxf(m0, v0), mn1 = fmaxf(m1, v1);
            float c0_ = __expf(m0 - mn0), c1_ = __expf(m1 - mn1);
            float p0 = __expf(v0 - mn0), p1 = __expf(v1 - mn1);
            l0 = l0 * c0_ + p0; a0 = a0 * c0_ + p0 * x0; m0 = mn0;
            l1 = l1 * c1_ + p1; a1 = a1 * c1_ + p1 * x1; m1 = mn1;
        }
        if (i < cnt) {
            int s0 = sidx[i];
            float x0 = bf2f(xl1[(size_t)s0 * HID + tid]);
            float e0 = x0 + xrd; e0 = (e0 >= 0.f) ? e0 : NEG_SLOPE * e0;
            float v0 = e0 * attv;
            v0 += __shfl_xor(v0, 16);
            v0 += __shfl_xor(v0, 8);
            v0 += __shfl_xor(v0, 4);
            v0 += __shfl_xor(v0, 2);
            v0 += __shfl_xor(v0, 1);
            float mn0 = fmaxf(m0, v0);
            float c0_ = __expf(m0 - mn0), p0 = __expf(v0 - mn0);
            l0 = l0 * c0_ + p0; a0 = a0 * c0_ + p0 * x0; m0 = mn0;
        }
    }
    // merge the two states
    float m = fmaxf(m0, m1);
    float e0 = __expf(m0 - m), e1 = __expf(m1 - m);
    float l = l0 * e0 + l1 * e1;
    float acc = a0 * e0 + a1 * e1;
    h1[(size_t)n * HID + tid] = acc / (l + 1e-16f) + bias1[tid];
}

// ---------------- BatchNorm stats / finalize ----------------
__global__ __launch_bounds__(320) void bnstats_kernel(const float* __restrict__ h1,
        double* __restrict__ bn_sum, double* __restrict__ bn_sq) {
    const int tid = threadIdx.x;
    double s = 0.0, q = 0.0;
    for (int n = blockIdx.x; n < NN; n += gridDim.x) {
        float v = h1[(size_t)n * HID + tid];
        s += v; q += (double)v * v;
    }
    atomicAdd(&bn_sum[tid], s);
    atomicAdd(&bn_sq[tid], q);
}

__global__ void bnfinal_kernel(const double* __restrict__ bn_sum, const double* __restrict__ bn_sq,
        const float* __restrict__ gamma, const float* __restrict__ beta,
        float* __restrict__ scale, float* __restrict__ shift) {
    int c = threadIdx.x;
    double mean = bn_sum[c] / (double)NN;
    double var  = bn_sq[c] / (double)NN - mean * mean;
    float sc = gamma[c] * rsqrtf((float)var + EPS_BN);
    scale[c] = sc;
    shift[c] = beta[c] - (float)mean * sc;
}

// ---------------- GEMM2 fused with BN-apply + PReLU: 16 rows/block ----------------
__global__ __launch_bounds__(256) void gemm2_kernel(const float* __restrict__ h1,
        const float* __restrict__ scale, const float* __restrict__ shift,
        const float* __restrict__ prelu_a,
        const float* __restrict__ Wl2, const float* __restrict__ bl2,
        const float* __restrict__ Wr2, const float* __restrict__ br2,
        float* __restrict__ xl2, float* __restrict__ xr2)
{
    __shared__ float hs[16][HID];
    const int tid = threadIdx.x;
    const int r0 = blockIdx.x * 16;
    const float a = prelu_a[0];
    // transform 16x320 rows: BN scale/shift + PReLU into LDS
    for (int f = tid; f < 1280; f += 256) {
        int fi = f << 2;
        int row = fi / HID, col = fi % HID;     // HID%4==0: float4 stays in-row
        float4 hv = *(const float4*)(h1 + (size_t)(r0 + row) * HID + col);
        float4 sc = *(const float4*)(scale + col);
        float4 sh = *(const float4*)(shift + col);
        float4 o;
        o.x = hv.x * sc.x + sh.x; o.x = (o.x >= 0.f) ? o.x : a * o.x;
        o.y = hv.y * sc.y + sh.y; o.y = (o.y >= 0.f) ? o.y : a * o.y;
        o.z = hv.z * sc.z + sh.z; o.z = (o.z >= 0.f) ? o.z : a * o.z;
        o.w = hv.w * sc.w + sh.w; o.w = (o.w >= 0.f) ? o.w : a * o.w;
        *(float4*)&hs[row][col] = o;
    }
    __syncthreads();
    const int c = tid & 31;
    const int tr = tid >> 5;         // rows tr and tr+8
    float aL0 = bl2[c], aL1 = aL0;
    float aR0 = br2[c], aR1 = aR0;
    #pragma unroll 4
    for (int k = 0; k < HID; ++k) {
        float w_l = Wl2[k * DOUT + c];
        float w_r = Wr2[k * DOUT + c];
        float h0 = hs[tr][k], h1v = hs[tr + 8][k];
        aL0 = fmaf(h0, w_l, aL0); aL1 = fmaf(h1v, w_l, aL1);
        aR0 = fmaf(h0, w_r, aR0); aR1 = fmaf(h1v, w_r, aR1);
    }
    size_t g0 = (size_t)(r0 + tr) * DOUT + c;
    size_t g1 = (size_t)(r0 + tr + 8) * DOUT + c;
    xl2[g0] = aL0; xr2[g0] = aR0;
    xl2[g1] = aL1; xr2[g1] = aR1;
}

// ---------------- Layer-2 aggregation: half-wave edge split + log_softmax ----------------
__global__ __launch_bounds__(64) void agg2_kernel(
    const float* __restrict__ xl2, const float* __restrict__ xr2,
    const int* __restrict__ row_ptr, const int* __restrict__ sorted_src,
    const float* __restrict__ att2, const float* __restrict__ bias2,
    float* __restrict__ out)
{
    __shared__ int sidx[64];
    const int n = blockIdx.x;
    const int lane = threadIdx.x;
    const int c = lane & 31;
    const int half = lane >> 5;       // lanes 0-31: edge i, lanes 32-63: edge i+1
    const float attv = att2[c];
    const float xrd = xr2[(size_t)n * DOUT + c];
    const int rp = row_ptr[n];
    const int deg = row_ptr[n + 1] - rp;
    float m = -1e30f, l = 0.f, acc = 0.f;
    for (int base = 0; base < deg; base += 64) {
        int cnt = min(64, deg - base);
        __syncthreads();
        if (lane < cnt) sidx[lane] = sorted_src[rp + base + lane];
        __syncthreads();
        for (int i = 0; i < cnt; i += 2) {
            int idx = i + half;
            bool valid = idx < cnt;
            int s = valid ? sidx[idx] : 0;
            float xls = valid ? xl2[(size_t)s * DOUT + c] : 0.f;
            float e = xls + xrd; e = (e >= 0.f) ? e : NEG_SLOPE * e;
            float v = e * attv;
            v += __shfl_xor(v, 16);
            v += __shfl_xor(v, 8);
            v += __shfl_xor(v, 4);
            v += __shfl_xor(v, 2);
            v += __shfl_xor(v, 1);
            if (valid) {
                float mn = fmaxf(m, v);
                float corr = __expf(m - mn);
                float p = __expf(v - mn);
                l = l * corr + p;
                acc = acc * corr + p * xls;
                m = mn;
            }
        }
    }
    // merge halves
    float om = __shfl_xor(m, 32);
    float ol = __shfl_xor(l, 32);
    float oa = __shfl_xor(acc, 32);
    float mm = fmaxf(m, om);
    float ea = __expf(m - mm), eb = __expf(om - mm);
    l = l * ea + ol * eb;
    acc = acc * ea + oa * eb;

    float o = acc / (l + 1e-16f) + bias2[c];
    float mx = o;
    mx = fmaxf(mx, __shfl_xor(mx, 16));
    mx = fmaxf(mx, __shfl_xor(mx, 8));
    mx = fmaxf(mx, __shfl_xor(mx, 4));
    mx = fmaxf(mx, __shfl_xor(mx, 2));
    mx = fmaxf(mx, __shfl_xor(mx, 1));
    float pe = __expf(o - mx);
    float se = pe;
    se += __shfl_xor(se, 16);
    se += __shfl_xor(se, 8);
    se += __shfl_xor(se, 4);
    se += __shfl_xor(se, 2);
    se += __shfl_xor(se, 1);
    float lsm = o - mx - logf(se);
    if (lane < 32) {
        out[(size_t)n * DOUT + c] = o;                 // output 0
        out[(size_t)(NN + n) * DOUT + c] = lsm;        // output 1 (log_softmax)
    }
}

extern "C" void kernel_launch(void* const* d_in, const int* in_sizes, int n_in,
                              void* d_out, int out_size, void* d_ws, size_t ws_size,
                              hipStream_t stream)
{
    const float* x       = (const float*)d_in[0];
    const int*   ei      = (const int*)d_in[1];
    const float* Wl1     = (const float*)d_in[2];
    const float* bl1     = (const float*)d_in[3];
    const float* Wr1     = (const float*)d_in[4];
    const float* br1     = (const float*)d_in[5];
    const float* att1    = (const float*)d_in[6];
    const float* bias1   = (const float*)d_in[7];
    const float* gamma   = (const float*)d_in[8];
    const float* beta    = (const float*)d_in[9];
    const float* prelu_a = (const float*)d_in[10];
    const float* Wl2     = (const float*)d_in[11];
    const float* bl2     = (const float*)d_in[12];
    const float* Wr2     = (const float*)d_in[13];
    const float* br2     = (const float*)d_in[14];
    const float* att2    = (const float*)d_in[15];
    const float* bias2   = (const float*)d_in[16];
    const int* src = ei;
    const int* dst = ei + NE;

    // workspace layout (~130.4 MB)
    char* w = (char*)d_ws;
    unsigned short* xl1b = (unsigned short*)w;                  // NN*HID bf16 = 32 MB
    unsigned short* xr1b = xl1b + (size_t)NN * HID;             // 32 MB
    float* h1 = (float*)(xr1b + (size_t)NN * HID);              // NN*HID f32 = 64 MB
    char* small = (char*)(h1 + (size_t)NN * HID);               // offset 128,000,000 (8-aligned)
    double* bn_sum = (double*)small;              // HID
    double* bn_sq  = bn_sum + HID;                // HID
    float* scale   = (float*)(bn_sq + HID);       // HID
    float* shift   = scale + HID;                 // HID
    int* deg       = (int*)(shift + HID);         // NN
    int* cursor    = deg + NN;                    // NN
    int* sorted    = cursor + NN;                 // NE
    int* row_ptr   = sorted + NE;                 // NN+1
    // layer-2 buffers reuse the (dead-after-agg1) xl1b region
    float* xl2 = (float*)w;                                     // NN*DOUT f32 = 6.4 MB
    float* xr2 = (float*)(w + (size_t)NN * DOUT * 4);           // 6.4 MB

    hipMemsetAsync(deg, 0, NN * sizeof(int), stream);
    hipMemsetAsync(bn_sum, 0, 2 * HID * sizeof(double), stream);

    gemm1_kernel<<<dim3(HID / 32, (NN + 63) / 64), 256, 0, stream>>>(
        x, Wl1, bl1, Wr1, br1, xl1b, xr1b);
    hist_kernel<<<(NE + 255) / 256, 256, 0, stream>>>(dst, deg);
    scan_kernel<<<1, 1024, 0, stream>>>(deg, row_ptr, cursor);
    scatter_kernel<<<(NE + 255) / 256, 256, 0, stream>>>(src, dst, cursor, sorted);
    agg1_kernel<<<NN, HID, 0, stream>>>(xl1b, xr1b, row_ptr, sorted, att1, bias1, h1);
    bnstats_kernel<<<512, HID, 0, stream>>>(h1, bn_sum, bn_sq);
    bnfinal_kernel<<<1, HID, 0, stream>>>(bn_sum, bn_sq, gamma, beta, scale, shift);
    gemm2_kernel<<<NN / 16, 256, 0, stream>>>(h1, scale, shift, prelu_a,
        Wl2, bl2, Wr2, br2, xl2, xr2);
    agg2_kernel<<<NN, 64, 0, stream>>>(xl2, xr2, row_ptr, sorted, att2, bias2, (float*)d_out);
}

// Round 6
// 569.951 us; speedup vs baseline: 1.5906x; 1.1169x over previous
//
#include <hip/hip_runtime.h>
#include <hip/hip_bf16.h>

#define NN 50000
#define NE 400000
#define DIN 128
#define DH 32
#define NH 10
#define HID 320
#define DOUT 32
#define NEG_SLOPE 0.2f
#define EPS_BN 1e-5f

typedef __attribute__((ext_vector_type(8))) short short8;
typedef __attribute__((ext_vector_type(4))) float f32x4;

__device__ inline unsigned short f2bf(float f) {
    unsigned int u = __float_as_uint(f);
    u += 0x7fffu + ((u >> 16) & 1u);
    return (unsigned short)(u >> 16);
}
__device__ inline float bf2f(unsigned short u) {
    return __uint_as_float(((unsigned int)u) << 16);
}

// ---------------- GEMM1 (MFMA bf16): x[NN,128] @ {Wl,Wr}[128,320] + b -> bf16 xl1, xr1 ----
__global__ __launch_bounds__(256) void gemm1_kernel(
    const float* __restrict__ x,
    const float* __restrict__ Wl, const float* __restrict__ bl,
    const float* __restrict__ Wr, const float* __restrict__ br,
    unsigned short* __restrict__ xl1, unsigned short* __restrict__ xr1)
{
    __shared__ short xs[64 * 128];      // bf16 bits, XOR-swizzled (T2)
    __shared__ short wt[2][32 * 152];   // W^T per matrix: [col][k], pad 152 (2-way banks)
    const int tid = threadIdx.x;
    const int c0 = blockIdx.x * 32;
    const int r0 = blockIdx.y * 64;

    for (int ch = tid; ch < 2048; ch += 256) {
        int rr = ch >> 5, c4 = (ch & 31) << 2;
        float4 v = make_float4(0.f, 0.f, 0.f, 0.f);
        if (r0 + rr < NN) v = *(const float4*)(x + (size_t)(r0 + rr) * DIN + c4);
        short4 s;
        s.x = (short)f2bf(v.x); s.y = (short)f2bf(v.y);
        s.z = (short)f2bf(v.z); s.w = (short)f2bf(v.w);
        int u = (rr * 128 + c4) ^ ((rr & 7) << 3);
        *(short4*)&xs[u] = s;
    }
    for (int f = tid; f < 2048; f += 256) {
        int mat = f >> 10, fi = f & 1023;
        int k = fi >> 3, cq = (fi & 7) << 2;
        const float* Wp = mat ? Wr : Wl;
        float4 v = *(const float4*)(Wp + (size_t)k * HID + c0 + cq);
        short* dp = &wt[mat][0];
        dp[(cq + 0) * 152 + k] = (short)f2bf(v.x);
        dp[(cq + 1) * 152 + k] = (short)f2bf(v.y);
        dp[(cq + 2) * 152 + k] = (short)f2bf(v.z);
        dp[(cq + 3) * 152 + k] = (short)f2bf(v.w);
    }
    __syncthreads();

    const int w = tid >> 6, lane = tid & 63;
    const int arow = w * 16 + (lane & 15);
    const int kgrp = (lane >> 4) << 3;
    f32x4 acc00 = {}, acc01 = {}, acc10 = {}, acc11 = {};
    #pragma unroll
    for (int kk = 0; kk < 4; ++kk) {
        int au = (arow * 128 + kk * 32 + kgrp) ^ ((arow & 7) << 3);
        short8 a = *(short8*)&xs[au];
        int bu0 = (lane & 15) * 152 + kk * 32 + kgrp;
        int bu1 = (16 + (lane & 15)) * 152 + kk * 32 + kgrp;
        short8 bL0 = *(short8*)&wt[0][bu0];
        short8 bL1 = *(short8*)&wt[0][bu1];
        short8 bR0 = *(short8*)&wt[1][bu0];
        short8 bR1 = *(short8*)&wt[1][bu1];
        acc00 = __builtin_amdgcn_mfma_f32_16x16x32_bf16(a, bL0, acc00, 0, 0, 0);
        acc01 = __builtin_amdgcn_mfma_f32_16x16x32_bf16(a, bL1, acc01, 0, 0, 0);
        acc10 = __builtin_amdgcn_mfma_f32_16x16x32_bf16(a, bR0, acc10, 0, 0, 0);
        acc11 = __builtin_amdgcn_mfma_f32_16x16x32_bf16(a, bR1, acc11, 0, 0, 0);
    }
    const int orow = r0 + w * 16 + ((lane >> 4) << 2);
    #pragma unroll
    for (int cf = 0; cf < 2; ++cf) {
        const int col = c0 + cf * 16 + (lane & 15);
        const float blv = bl[col], brv = br[col];
        const f32x4 aL = cf ? acc01 : acc00;
        const f32x4 aR = cf ? acc11 : acc10;
        #pragma unroll
        for (int reg = 0; reg < 4; ++reg) {
            int row = orow + reg;
            if (row < NN) {
                xl1[(size_t)row * HID + col] = f2bf(aL[reg] + blv);
                xr1[(size_t)row * HID + col] = f2bf(aR[reg] + brv);
            }
        }
    }
}

// ---------------- CSR build ----------------
__global__ void hist_kernel(const int* __restrict__ dst, int* __restrict__ deg) {
    int e = blockIdx.x * blockDim.x + threadIdx.x;
    if (e < NE) atomicAdd(&deg[dst[e]], 1);
}

__global__ __launch_bounds__(1024) void scan_kernel(const int* __restrict__ deg,
        int* __restrict__ row_ptr, int* __restrict__ cursor) {
    __shared__ int sums[1024];
    const int tid = threadIdx.x;
    const int CH = (NN + 1023) / 1024;  // 49
    const int st = tid * CH;
    const int en = min(st + CH, NN);
    int s = 0;
    for (int i = st; i < en; ++i) s += deg[i];
    sums[tid] = s;
    __syncthreads();
    for (int off = 1; off < 1024; off <<= 1) {
        int v = (tid >= off) ? sums[tid - off] : 0;
        __syncthreads();
        sums[tid] += v;
        __syncthreads();
    }
    int run = (tid == 0) ? 0 : sums[tid - 1];
    for (int i = st; i < en; ++i) {
        row_ptr[i] = run; cursor[i] = run; run += deg[i];
    }
    if (tid == 1023) row_ptr[NN] = sums[1023];
}

__global__ void scatter_kernel(const int* __restrict__ src, const int* __restrict__ dst,
        int* __restrict__ cursor, int* __restrict__ sorted_src) {
    int e = blockIdx.x * blockDim.x + threadIdx.x;
    if (e < NE) {
        int d = dst[e];
        int p = atomicAdd(&cursor[d], 1);
        sorted_src[p] = src[e];
    }
}

// ---------------- Layer-1 aggregation: no-max softmax, 4-edge ILP, barrier-free ----------
__global__ __launch_bounds__(320) void agg1_kernel(
    const unsigned short* __restrict__ xl1, const unsigned short* __restrict__ xr1,
    const int* __restrict__ row_ptr, const int* __restrict__ sorted_src,
    const float* __restrict__ att1, const float* __restrict__ bias1,
    unsigned short* __restrict__ h1b)
{
    const int n = blockIdx.x;
    const int tid = threadIdx.x;              // tid = h*32 + c
    const float attv = att1[tid];
    const float xrd  = bf2f(xr1[(size_t)n * HID + tid]);
    const int rp = row_ptr[n];
    const int deg = row_ptr[n + 1] - rp;
    const int* sp = sorted_src + rp;
    float l0 = 0.f, l1 = 0.f, l2 = 0.f, l3 = 0.f;
    float a0 = 0.f, a1 = 0.f, a2 = 0.f, a3 = 0.f;
    int i = 0;
    for (; i + 4 <= deg; i += 4) {
        int s0 = sp[i], s1 = sp[i + 1], s2 = sp[i + 2], s3 = sp[i + 3];
        float x0 = bf2f(xl1[(size_t)s0 * HID + tid]);
        float x1 = bf2f(xl1[(size_t)s1 * HID + tid]);
        float x2 = bf2f(xl1[(size_t)s2 * HID + tid]);
        float x3 = bf2f(xl1[(size_t)s3 * HID + tid]);
        float e0 = x0 + xrd; e0 = (e0 >= 0.f) ? e0 : NEG_SLOPE * e0;
        float e1 = x1 + xrd; e1 = (e1 >= 0.f) ? e1 : NEG_SLOPE * e1;
        float e2 = x2 + xrd; e2 = (e2 >= 0.f) ? e2 : NEG_SLOPE * e2;
        float e3 = x3 + xrd; e3 = (e3 >= 0.f) ? e3 : NEG_SLOPE * e3;
        float v0 = e0 * attv, v1 = e1 * attv, v2 = e2 * attv, v3 = e3 * attv;
        v0 += __shfl_xor(v0, 16); v1 += __shfl_xor(v1, 16); v2 += __shfl_xor(v2, 16); v3 += __shfl_xor(v3, 16);
        v0 += __shfl_xor(v0, 8);  v1 += __shfl_xor(v1, 8);  v2 += __shfl_xor(v2, 8);  v3 += __shfl_xor(v3, 8);
        v0 += __shfl_xor(v0, 4);  v1 += __shfl_xor(v1, 4);  v2 += __shfl_xor(v2, 4);  v3 += __shfl_xor(v3, 4);
        v0 += __shfl_xor(v0, 2);  v1 += __shfl_xor(v1, 2);  v2 += __shfl_xor(v2, 2);  v3 += __shfl_xor(v3, 2);
        v0 += __shfl_xor(v0, 1);  v1 += __shfl_xor(v1, 1);  v2 += __shfl_xor(v2, 1);  v3 += __shfl_xor(v3, 1);
        float p0 = __expf(v0), p1 = __expf(v1), p2 = __expf(v2), p3 = __expf(v3);
        l0 += p0; a0 = fmaf(p0, x0, a0);
        l1 += p1; a1 = fmaf(p1, x1, a1);
        l2 += p2; a2 = fmaf(p2, x2, a2);
        l3 += p3; a3 = fmaf(p3, x3, a3);
    }
    for (; i < deg; ++i) {
        int s = sp[i];
        float xx = bf2f(xl1[(size_t)s * HID + tid]);
        float e = xx + xrd; e = (e >= 0.f) ? e : NEG_SLOPE * e;
        float v = e * attv;
        v += __shfl_xor(v, 16);
        v += __shfl_xor(v, 8);
        v += __shfl_xor(v, 4);
        v += __shfl_xor(v, 2);
        v += __shfl_xor(v, 1);
        float p = __expf(v);
        l0 += p; a0 = fmaf(p, xx, a0);
    }
    float l = (l0 + l1) + (l2 + l3);
    float acc = (a0 + a1) + (a2 + a3);
    h1b[(size_t)n * HID + tid] = f2bf(acc / (l + 1e-16f) + bias1[tid]);
}

// ---------------- BatchNorm stats / finalize ----------------
__global__ __launch_bounds__(320) void bnstats_kernel(const unsigned short* __restrict__ h1b,
        double* __restrict__ bn_sum, double* __restrict__ bn_sq) {
    const int tid = threadIdx.x;
    double s = 0.0, q = 0.0;
    for (int n = blockIdx.x; n < NN; n += gridDim.x) {
        float v = bf2f(h1b[(size_t)n * HID + tid]);
        s += v; q += (double)v * v;
    }
    atomicAdd(&bn_sum[tid], s);
    atomicAdd(&bn_sq[tid], q);
}

__global__ void bnfinal_kernel(const double* __restrict__ bn_sum, const double* __restrict__ bn_sq,
        const float* __restrict__ gamma, const float* __restrict__ beta,
        float* __restrict__ scale, float* __restrict__ shift) {
    int c = threadIdx.x;
    double mean = bn_sum[c] / (double)NN;
    double var  = bn_sq[c] / (double)NN - mean * mean;
    float sc = gamma[c] * rsqrtf((float)var + EPS_BN);
    scale[c] = sc;
    shift[c] = beta[c] - (float)mean * sc;
}

// ---------------- precast: Wl2/Wr2 f32[k][c] -> bf16 transposed [c][k] ----------------
__global__ void precast_w2(const float* __restrict__ Wl2, const float* __restrict__ Wr2,
        unsigned short* __restrict__ wl2t, unsigned short* __restrict__ wr2t) {
    int idx = blockIdx.x * 256 + threadIdx.x;
    if (idx < HID * DOUT) {
        int c = idx / HID, k = idx - c * HID;
        wl2t[idx] = f2bf(Wl2[k * DOUT + c]);
        wr2t[idx] = f2bf(Wr2[k * DOUT + c]);
    }
}

// ---------------- GEMM2 (MFMA bf16) fused BN+PReLU: h[NN,320] @ [320,32] -> xl2, xr2 -----
__global__ __launch_bounds__(256) void gemm2_kernel(
    const unsigned short* __restrict__ h1b,
    const float* __restrict__ scale, const float* __restrict__ shift,
    const float* __restrict__ prelu_a,
    const unsigned short* __restrict__ wl2t, const unsigned short* __restrict__ wr2t,
    const float* __restrict__ bl2, const float* __restrict__ br2,
    float* __restrict__ xl2, float* __restrict__ xr2)
{
    __shared__ short hs[64 * 320];   // transformed rows, bf16, XOR-swizzled
    const int tid = threadIdx.x;
    const int r0 = blockIdx.x * 64;
    const float a = prelu_a[0];
    // stage + BN + PReLU: 64 rows x 320 = 5120 ushort4
    for (int f = tid; f < 5120; f += 256) {
        int e = f << 2;
        int rr = e / 320;
        int cc = e - rr * 320;
        ushort4 hv = make_ushort4(0, 0, 0, 0);
        if (r0 + rr < NN) hv = *(const ushort4*)(h1b + (size_t)(r0 + rr) * HID + cc);
        float4 sc = *(const float4*)(scale + cc);
        float4 sh = *(const float4*)(shift + cc);
        float o0 = bf2f(hv.x) * sc.x + sh.x; o0 = (o0 >= 0.f) ? o0 : a * o0;
        float o1 = bf2f(hv.y) * sc.y + sh.y; o1 = (o1 >= 0.f) ? o1 : a * o1;
        float o2 = bf2f(hv.z) * sc.z + sh.z; o2 = (o2 >= 0.f) ? o2 : a * o2;
        float o3 = bf2f(hv.w) * sc.w + sh.w; o3 = (o3 >= 0.f) ? o3 : a * o3;
        short4 s;
        s.x = (short)f2bf(o0); s.y = (short)f2bf(o1);
        s.z = (short)f2bf(o2); s.w = (short)f2bf(o3);
        int u = (rr * 320 + cc) ^ ((rr & 7) << 3);
        *(short4*)&hs[u] = s;
    }
    __syncthreads();

    const int w = tid >> 6, lane = tid & 63;
    const int arow = w * 16 + (lane & 15);
    const int kgrp = (lane >> 4) << 3;
    const int bcol = lane & 15;
    f32x4 acc00 = {}, acc01 = {}, acc10 = {}, acc11 = {};
    #pragma unroll
    for (int kk = 0; kk < 10; ++kk) {
        int au = (arow * 320 + kk * 32 + kgrp) ^ ((arow & 7) << 3);
        short8 afr = *(short8*)&hs[au];
        const int ko = kk * 32 + kgrp;
        short8 bL0 = *(const short8*)(wl2t + bcol * HID + ko);
        short8 bL1 = *(const short8*)(wl2t + (16 + bcol) * HID + ko);
        short8 bR0 = *(const short8*)(wr2t + bcol * HID + ko);
        short8 bR1 = *(const short8*)(wr2t + (16 + bcol) * HID + ko);
        acc00 = __builtin_amdgcn_mfma_f32_16x16x32_bf16(afr, bL0, acc00, 0, 0, 0);
        acc01 = __builtin_amdgcn_mfma_f32_16x16x32_bf16(afr, bL1, acc01, 0, 0, 0);
        acc10 = __builtin_amdgcn_mfma_f32_16x16x32_bf16(afr, bR0, acc10, 0, 0, 0);
        acc11 = __builtin_amdgcn_mfma_f32_16x16x32_bf16(afr, bR1, acc11, 0, 0, 0);
    }
    const int orow = r0 + w * 16 + ((lane >> 4) << 2);
    #pragma unroll
    for (int cf = 0; cf < 2; ++cf) {
        const int col = cf * 16 + bcol;
        const float blv = bl2[col], brv = br2[col];
        const f32x4 aL = cf ? acc01 : acc00;
        const f32x4 aR = cf ? acc11 : acc10;
        #pragma unroll
        for (int reg = 0; reg < 4; ++reg) {
            int row = orow + reg;
            if (row < NN) {
                xl2[(size_t)row * DOUT + col] = aL[reg] + blv;
                xr2[(size_t)row * DOUT + col] = aR[reg] + brv;
            }
        }
    }
}

// ---------------- Layer-2 aggregation: no-max, half-wave split, barrier-free -------------
__global__ __launch_bounds__(64) void agg2_kernel(
    const float* __restrict__ xl2, const float* __restrict__ xr2,
    const int* __restrict__ row_ptr, const int* __restrict__ sorted_src,
    const float* __restrict__ att2, const float* __restrict__ bias2,
    float* __restrict__ out)
{
    const int n = blockIdx.x;
    const int lane = threadIdx.x;
    const int c = lane & 31;
    const int half = lane >> 5;       // lanes 0-31: even edges, 32-63: odd edges
    const float attv = att2[c];
    const float xrd = xr2[(size_t)n * DOUT + c];
    const int rp = row_ptr[n];
    const int deg = row_ptr[n + 1] - rp;
    const int* sp = sorted_src + rp;
    float l = 0.f, acc = 0.f;
    for (int i = half; i < deg; i += 2) {
        int s = sp[i];
        float xls = xl2[(size_t)s * DOUT + c];
        float e = xls + xrd; e = (e >= 0.f) ? e : NEG_SLOPE * e;
        float v = e * attv;
        v += __shfl_xor(v, 16);
        v += __shfl_xor(v, 8);
        v += __shfl_xor(v, 4);
        v += __shfl_xor(v, 2);
        v += __shfl_xor(v, 1);
        float p = __expf(v);
        l += p;
        acc = fmaf(p, xls, acc);
    }
    l += __shfl_xor(l, 32);
    acc += __shfl_xor(acc, 32);

    float o = acc / (l + 1e-16f) + bias2[c];
    float mx = o;
    mx = fmaxf(mx, __shfl_xor(mx, 16));
    mx = fmaxf(mx, __shfl_xor(mx, 8));
    mx = fmaxf(mx, __shfl_xor(mx, 4));
    mx = fmaxf(mx, __shfl_xor(mx, 2));
    mx = fmaxf(mx, __shfl_xor(mx, 1));
    float pe = __expf(o - mx);
    float se = pe;
    se += __shfl_xor(se, 16);
    se += __shfl_xor(se, 8);
    se += __shfl_xor(se, 4);
    se += __shfl_xor(se, 2);
    se += __shfl_xor(se, 1);
    float lsm = o - mx - logf(se);
    if (lane < 32) {
        out[(size_t)n * DOUT + c] = o;
        out[(size_t)(NN + n) * DOUT + c] = lsm;
    }
}

extern "C" void kernel_launch(void* const* d_in, const int* in_sizes, int n_in,
                              void* d_out, int out_size, void* d_ws, size_t ws_size,
                              hipStream_t stream)
{
    const float* x       = (const float*)d_in[0];
    const int*   ei      = (const int*)d_in[1];
    const float* Wl1     = (const float*)d_in[2];
    const float* bl1     = (const float*)d_in[3];
    const float* Wr1     = (const float*)d_in[4];
    const float* br1     = (const float*)d_in[5];
    const float* att1    = (const float*)d_in[6];
    const float* bias1   = (const float*)d_in[7];
    const float* gamma   = (const float*)d_in[8];
    const float* beta    = (const float*)d_in[9];
    const float* prelu_a = (const float*)d_in[10];
    const float* Wl2     = (const float*)d_in[11];
    const float* bl2     = (const float*)d_in[12];
    const float* Wr2     = (const float*)d_in[13];
    const float* br2     = (const float*)d_in[14];
    const float* att2    = (const float*)d_in[15];
    const float* bias2   = (const float*)d_in[16];
    const int* src = ei;
    const int* dst = ei + NE;

    // workspace layout (~98 MB)
    char* w = (char*)d_ws;
    unsigned short* xl1b = (unsigned short*)w;                  // NN*HID bf16 = 32 MB
    unsigned short* xr1b = xl1b + (size_t)NN * HID;             // 32 MB
    unsigned short* h1b  = xr1b + (size_t)NN * HID;             // 32 MB
    char* small = (char*)(h1b + (size_t)NN * HID);              // offset 96,000,000 (16-aligned)
    double* bn_sum = (double*)small;                            // 320 dbl
    double* bn_sq  = bn_sum + HID;                              // 320 dbl
    float* scale   = (float*)(bn_sq + HID);                     // 320 f
    float* shift   = scale + HID;                               // 320 f
    unsigned short* wl2t = (unsigned short*)(shift + HID);      // 10240 bf16 (16B-aligned)
    unsigned short* wr2t = wl2t + HID * DOUT;                   // 10240 bf16
    int* deg       = (int*)(wr2t + HID * DOUT);                 // NN
    int* cursor    = deg + NN;                                  // NN
    int* sorted    = cursor + NN;                               // NE
    int* row_ptr   = sorted + NE;                               // NN+1
    // layer-2 activation buffers reuse the (dead-after-agg1) xl1b region
    float* xl2 = (float*)w;                                     // 6.4 MB
    float* xr2 = (float*)(w + (size_t)NN * DOUT * 4);           // 6.4 MB

    hipMemsetAsync(deg, 0, NN * sizeof(int), stream);
    hipMemsetAsync(bn_sum, 0, 2 * HID * sizeof(double), stream);

    precast_w2<<<(HID * DOUT + 255) / 256, 256, 0, stream>>>(Wl2, Wr2, wl2t, wr2t);
    gemm1_kernel<<<dim3(HID / 32, (NN + 63) / 64), 256, 0, stream>>>(
        x, Wl1, bl1, Wr1, br1, xl1b, xr1b);
    hist_kernel<<<(NE + 255) / 256, 256, 0, stream>>>(dst, deg);
    scan_kernel<<<1, 1024, 0, stream>>>(deg, row_ptr, cursor);
    scatter_kernel<<<(NE + 255) / 256, 256, 0, stream>>>(src, dst, cursor, sorted);
    agg1_kernel<<<NN, HID, 0, stream>>>(xl1b, xr1b, row_ptr, sorted, att1, bias1, h1b);
    bnstats_kernel<<<512, HID, 0, stream>>>(h1b, bn_sum, bn_sq);
    bnfinal_kernel<<<1, HID, 0, stream>>>(bn_sum, bn_sq, gamma, beta, scale, shift);
    gemm2_kernel<<<(NN + 63) / 64, 256, 0, stream>>>(h1b, scale, shift, prelu_a,
        wl2t, wr2t, bl2, br2, xl2, xr2);
    agg2_kernel<<<NN, 64, 0, stream>>>(xl2, xr2, row_ptr, sorted, att2, bias2, (float*)d_out);
}

// Round 8
// 476.313 us; speedup vs baseline: 1.9033x; 1.1966x over previous
//
#include <hip/hip_runtime.h>
#include <hip/hip_bf16.h>

#define NN 50000
#define NE 400000
#define DIN 128
#define DH 32
#define NH 10
#define HID 320
#define DOUT 32
#define NEG_SLOPE 0.2f
#define EPS_BN 1e-5f

typedef __attribute__((ext_vector_type(8))) short short8;
typedef __attribute__((ext_vector_type(4))) float f32x4;

__device__ inline unsigned short f2bf(float f) {
    unsigned int u = __float_as_uint(f);
    u += 0x7fffu + ((u >> 16) & 1u);
    return (unsigned short)(u >> 16);
}
__device__ inline float bf2f(unsigned short u) {
    return __uint_as_float(((unsigned int)u) << 16);
}
__device__ inline float bflo(unsigned int u) {   // low bf16 of packed pair
    return __uint_as_float(u << 16);
}
__device__ inline float bfhi(unsigned int u) {   // high bf16 of packed pair
    return __uint_as_float(u & 0xffff0000u);
}
__device__ inline float lrelu(float x) { return fmaxf(x, NEG_SLOPE * x); }

// ---------------- GEMM1 (MFMA bf16): x[NN,128] @ {Wl,Wr}[128,320] + b -> bf16 xl1, xr1 ----
__global__ __launch_bounds__(256) void gemm1_kernel(
    const float* __restrict__ x,
    const float* __restrict__ Wl, const float* __restrict__ bl,
    const float* __restrict__ Wr, const float* __restrict__ br,
    unsigned short* __restrict__ xl1, unsigned short* __restrict__ xr1)
{
    __shared__ short xs[64 * 128];      // bf16 bits, XOR-swizzled (T2)
    __shared__ short wt[2][32 * 152];   // W^T per matrix: [col][k], pad 152
    const int tid = threadIdx.x;
    const int c0 = blockIdx.x * 32;
    const int r0 = blockIdx.y * 64;

    for (int ch = tid; ch < 2048; ch += 256) {
        int rr = ch >> 5, c4 = (ch & 31) << 2;
        float4 v = make_float4(0.f, 0.f, 0.f, 0.f);
        if (r0 + rr < NN) v = *(const float4*)(x + (size_t)(r0 + rr) * DIN + c4);
        short4 s;
        s.x = (short)f2bf(v.x); s.y = (short)f2bf(v.y);
        s.z = (short)f2bf(v.z); s.w = (short)f2bf(v.w);
        int u = (rr * 128 + c4) ^ ((rr & 7) << 3);
        *(short4*)&xs[u] = s;
    }
    for (int f = tid; f < 2048; f += 256) {
        int mat = f >> 10, fi = f & 1023;
        int k = fi >> 3, cq = (fi & 7) << 2;
        const float* Wp = mat ? Wr : Wl;
        float4 v = *(const float4*)(Wp + (size_t)k * HID + c0 + cq);
        short* dp = &wt[mat][0];
        dp[(cq + 0) * 152 + k] = (short)f2bf(v.x);
        dp[(cq + 1) * 152 + k] = (short)f2bf(v.y);
        dp[(cq + 2) * 152 + k] = (short)f2bf(v.z);
        dp[(cq + 3) * 152 + k] = (short)f2bf(v.w);
    }
    __syncthreads();

    const int w = tid >> 6, lane = tid & 63;
    const int arow = w * 16 + (lane & 15);
    const int kgrp = (lane >> 4) << 3;
    f32x4 acc00 = {}, acc01 = {}, acc10 = {}, acc11 = {};
    #pragma unroll
    for (int kk = 0; kk < 4; ++kk) {
        int au = (arow * 128 + kk * 32 + kgrp) ^ ((arow & 7) << 3);
        short8 a = *(short8*)&xs[au];
        int bu0 = (lane & 15) * 152 + kk * 32 + kgrp;
        int bu1 = (16 + (lane & 15)) * 152 + kk * 32 + kgrp;
        short8 bL0 = *(short8*)&wt[0][bu0];
        short8 bL1 = *(short8*)&wt[0][bu1];
        short8 bR0 = *(short8*)&wt[1][bu0];
        short8 bR1 = *(short8*)&wt[1][bu1];
        acc00 = __builtin_amdgcn_mfma_f32_16x16x32_bf16(a, bL0, acc00, 0, 0, 0);
        acc01 = __builtin_amdgcn_mfma_f32_16x16x32_bf16(a, bL1, acc01, 0, 0, 0);
        acc10 = __builtin_amdgcn_mfma_f32_16x16x32_bf16(a, bR0, acc10, 0, 0, 0);
        acc11 = __builtin_amdgcn_mfma_f32_16x16x32_bf16(a, bR1, acc11, 0, 0, 0);
    }
    const int orow = r0 + w * 16 + ((lane >> 4) << 2);
    #pragma unroll
    for (int cf = 0; cf < 2; ++cf) {
        const int col = c0 + cf * 16 + (lane & 15);
        const float blv = bl[col], brv = br[col];
        const f32x4 aL = cf ? acc01 : acc00;
        const f32x4 aR = cf ? acc11 : acc10;
        #pragma unroll
        for (int reg = 0; reg < 4; ++reg) {
            int row = orow + reg;
            if (row < NN) {
                xl1[(size_t)row * HID + col] = f2bf(aL[reg] + blv);
                xr1[(size_t)row * HID + col] = f2bf(aR[reg] + brv);
            }
        }
    }
}

// ---------------- CSR build ----------------
__global__ void hist_kernel(const int* __restrict__ dst, int* __restrict__ deg) {
    int e = blockIdx.x * blockDim.x + threadIdx.x;
    if (e < NE) atomicAdd(&deg[dst[e]], 1);
}

__global__ __launch_bounds__(1024) void scan_kernel(const int* __restrict__ deg,
        int* __restrict__ row_ptr, int* __restrict__ cursor) {
    __shared__ int sums[1024];
    const int tid = threadIdx.x;
    const int CH = (NN + 1023) / 1024;  // 49
    const int st = tid * CH;
    const int en = min(st + CH, NN);
    int s = 0;
    for (int i = st; i < en; ++i) s += deg[i];
    sums[tid] = s;
    __syncthreads();
    for (int off = 1; off < 1024; off <<= 1) {
        int v = (tid >= off) ? sums[tid - off] : 0;
        __syncthreads();
        sums[tid] += v;
        __syncthreads();
    }
    int run = (tid == 0) ? 0 : sums[tid - 1];
    for (int i = st; i < en; ++i) {
        row_ptr[i] = run; cursor[i] = run; run += deg[i];
    }
    if (tid == 1023) row_ptr[NN] = sums[1023];
}

__global__ void scatter_kernel(const int* __restrict__ src, const int* __restrict__ dst,
        int* __restrict__ cursor, int* __restrict__ sorted_src) {
    int e = blockIdx.x * blockDim.x + threadIdx.x;
    if (e < NE) {
        int d = dst[e];
        int p = atomicAdd(&cursor[d], 1);
        sorted_src[p] = src[e];
    }
}

// ---------------- Layer-1 aggregation: 4 nodes/block, 8 lanes/head, 4 ch/lane -----------
__global__ __launch_bounds__(320) void agg1_kernel(
    const unsigned short* __restrict__ xl1, const unsigned short* __restrict__ xr1,
    const int* __restrict__ row_ptr, const int* __restrict__ sorted_src,
    const float* __restrict__ att1, const float* __restrict__ bias1,
    unsigned short* __restrict__ h1b)
{
    const int t = threadIdx.x;
    const int nsub = t / 80;              // 0..3
    const int r = t - nsub * 80;          // 0..79
    const int h = r >> 3;                 // 0..9
    const int l8 = r & 7;                 // 0..7
    const int c0 = h * 32 + l8 * 4;       // first of 4 channels
    const int n = blockIdx.x * 4 + nsub;  // NN % 4 == 0

    const float4 at = *(const float4*)(att1 + c0);
    const unsigned rbase = (unsigned)n * HID + c0;
    uint2 xr4 = *(const uint2*)(xr1 + rbase);
    const float xr0 = bflo(xr4.x), xr1f = bfhi(xr4.x);
    const float xr2 = bflo(xr4.y), xr3 = bfhi(xr4.y);

    const int rp = row_ptr[n];
    const int deg = row_ptr[n + 1] - rp;
    const int* sp = sorted_src + rp;

    float l = 0.f, ac0 = 0.f, ac1 = 0.f, ac2 = 0.f, ac3 = 0.f;
    int i = 0;
    for (; i + 2 <= deg; i += 2) {
        unsigned offA = (unsigned)sp[i] * HID + c0;
        unsigned offB = (unsigned)sp[i + 1] * HID + c0;
        uint2 ua = *(const uint2*)(xl1 + offA);
        uint2 ub = *(const uint2*)(xl1 + offB);
        float xA0 = bflo(ua.x), xA1 = bfhi(ua.x), xA2 = bflo(ua.y), xA3 = bfhi(ua.y);
        float xB0 = bflo(ub.x), xB1 = bfhi(ub.x), xB2 = bflo(ub.y), xB3 = bfhi(ub.y);
        float vA = lrelu(xA0 + xr0) * at.x;
        vA = fmaf(lrelu(xA1 + xr1f), at.y, vA);
        vA = fmaf(lrelu(xA2 + xr2), at.z, vA);
        vA = fmaf(lrelu(xA3 + xr3), at.w, vA);
        float vB = lrelu(xB0 + xr0) * at.x;
        vB = fmaf(lrelu(xB1 + xr1f), at.y, vB);
        vB = fmaf(lrelu(xB2 + xr2), at.z, vB);
        vB = fmaf(lrelu(xB3 + xr3), at.w, vB);
        vA += __shfl_xor(vA, 1); vB += __shfl_xor(vB, 1);
        vA += __shfl_xor(vA, 2); vB += __shfl_xor(vB, 2);
        vA += __shfl_xor(vA, 4); vB += __shfl_xor(vB, 4);
        float pA = __expf(vA), pB = __expf(vB);
        l += pA + pB;
        ac0 = fmaf(pA, xA0, ac0); ac0 = fmaf(pB, xB0, ac0);
        ac1 = fmaf(pA, xA1, ac1); ac1 = fmaf(pB, xB1, ac1);
        ac2 = fmaf(pA, xA2, ac2); ac2 = fmaf(pB, xB2, ac2);
        ac3 = fmaf(pA, xA3, ac3); ac3 = fmaf(pB, xB3, ac3);
    }
    if (i < deg) {
        unsigned offA = (unsigned)sp[i] * HID + c0;
        uint2 ua = *(const uint2*)(xl1 + offA);
        float xA0 = bflo(ua.x), xA1 = bfhi(ua.x), xA2 = bflo(ua.y), xA3 = bfhi(ua.y);
        float vA = lrelu(xA0 + xr0) * at.x;
        vA = fmaf(lrelu(xA1 + xr1f), at.y, vA);
        vA = fmaf(lrelu(xA2 + xr2), at.z, vA);
        vA = fmaf(lrelu(xA3 + xr3), at.w, vA);
        vA += __shfl_xor(vA, 1);
        vA += __shfl_xor(vA, 2);
        vA += __shfl_xor(vA, 4);
        float pA = __expf(vA);
        l += pA;
        ac0 = fmaf(pA, xA0, ac0); ac1 = fmaf(pA, xA1, ac1);
        ac2 = fmaf(pA, xA2, ac2); ac3 = fmaf(pA, xA3, ac3);
    }
    const float inv = 1.f / (l + 1e-16f);
    const float4 bi = *(const float4*)(bias1 + c0);
    uint2 outp;
    outp.x = (unsigned)f2bf(ac0 * inv + bi.x) | ((unsigned)f2bf(ac1 * inv + bi.y) << 16);
    outp.y = (unsigned)f2bf(ac2 * inv + bi.z) | ((unsigned)f2bf(ac3 * inv + bi.w) << 16);
    *(uint2*)(h1b + rbase) = outp;
}

// ---------------- BatchNorm stats / finalize ----------------
__global__ __launch_bounds__(320) void bnstats_kernel(const unsigned short* __restrict__ h1b,
        double* __restrict__ bn_sum, double* __restrict__ bn_sq) {
    const int tid = threadIdx.x;
    double s = 0.0, q = 0.0;
    for (int n = blockIdx.x; n < NN; n += gridDim.x) {
        float v = bf2f(h1b[(size_t)n * HID + tid]);
        s += v; q += (double)v * v;
    }
    atomicAdd(&bn_sum[tid], s);
    atomicAdd(&bn_sq[tid], q);
}

__global__ void bnfinal_kernel(const double* __restrict__ bn_sum, const double* __restrict__ bn_sq,
        const float* __restrict__ gamma, const float* __restrict__ beta,
        float* __restrict__ scale, float* __restrict__ shift) {
    int c = threadIdx.x;
    double mean = bn_sum[c] / (double)NN;
    double var  = bn_sq[c] / (double)NN - mean * mean;
    float sc = gamma[c] * rsqrtf((float)var + EPS_BN);
    scale[c] = sc;
    shift[c] = beta[c] - (float)mean * sc;
}

// ---------------- precast: Wl2/Wr2 f32[k][c] -> bf16 transposed [c][k] ----------------
__global__ void precast_w2(const float* __restrict__ Wl2, const float* __restrict__ Wr2,
        unsigned short* __restrict__ wl2t, unsigned short* __restrict__ wr2t) {
    int idx = blockIdx.x * 256 + threadIdx.x;
    if (idx < HID * DOUT) {
        int c = idx / HID, k = idx - c * HID;
        wl2t[idx] = f2bf(Wl2[k * DOUT + c]);
        wr2t[idx] = f2bf(Wr2[k * DOUT + c]);
    }
}

// ---------------- GEMM2 (MFMA bf16) fused BN+PReLU: h[NN,320] @ [320,32] -> xl2, xr2 -----
__global__ __launch_bounds__(256) void gemm2_kernel(
    const unsigned short* __restrict__ h1b,
    const float* __restrict__ scale, const float* __restrict__ shift,
    const float* __restrict__ prelu_a,
    const unsigned short* __restrict__ wl2t, const unsigned short* __restrict__ wr2t,
    const float* __restrict__ bl2, const float* __restrict__ br2,
    float* __restrict__ xl2, float* __restrict__ xr2)
{
    __shared__ short hs[64 * 320];   // transformed rows, bf16, XOR-swizzled
    const int tid = threadIdx.x;
    const int r0 = blockIdx.x * 64;
    const float a = prelu_a[0];
    for (int f = tid; f < 5120; f += 256) {
        int e = f << 2;
        int rr = e / 320;
        int cc = e - rr * 320;
        ushort4 hv = make_ushort4(0, 0, 0, 0);
        if (r0 + rr < NN) hv = *(const ushort4*)(h1b + (size_t)(r0 + rr) * HID + cc);
        float4 sc = *(const float4*)(scale + cc);
        float4 sh = *(const float4*)(shift + cc);
        float o0 = bf2f(hv.x) * sc.x + sh.x; o0 = (o0 >= 0.f) ? o0 : a * o0;
        float o1 = bf2f(hv.y) * sc.y + sh.y; o1 = (o1 >= 0.f) ? o1 : a * o1;
        float o2 = bf2f(hv.z) * sc.z + sh.z; o2 = (o2 >= 0.f) ? o2 : a * o2;
        float o3 = bf2f(hv.w) * sc.w + sh.w; o3 = (o3 >= 0.f) ? o3 : a * o3;
        short4 s;
        s.x = (short)f2bf(o0); s.y = (short)f2bf(o1);
        s.z = (short)f2bf(o2); s.w = (short)f2bf(o3);
        int u = (rr * 320 + cc) ^ ((rr & 7) << 3);
        *(short4*)&hs[u] = s;
    }
    __syncthreads();

    const int w = tid >> 6, lane = tid & 63;
    const int arow = w * 16 + (lane & 15);
    const int kgrp = (lane >> 4) << 3;
    const int bcol = lane & 15;
    f32x4 acc00 = {}, acc01 = {}, acc10 = {}, acc11 = {};
    #pragma unroll
    for (int kk = 0; kk < 10; ++kk) {
        int au = (arow * 320 + kk * 32 + kgrp) ^ ((arow & 7) << 3);
        short8 afr = *(short8*)&hs[au];
        const int ko = kk * 32 + kgrp;
        short8 bL0 = *(const short8*)(wl2t + bcol * HID + ko);
        short8 bL1 = *(const short8*)(wl2t + (16 + bcol) * HID + ko);
        short8 bR0 = *(const short8*)(wr2t + bcol * HID + ko);
        short8 bR1 = *(const short8*)(wr2t + (16 + bcol) * HID + ko);
        acc00 = __builtin_amdgcn_mfma_f32_16x16x32_bf16(afr, bL0, acc00, 0, 0, 0);
        acc01 = __builtin_amdgcn_mfma_f32_16x16x32_bf16(afr, bL1, acc01, 0, 0, 0);
        acc10 = __builtin_amdgcn_mfma_f32_16x16x32_bf16(afr, bR0, acc10, 0, 0, 0);
        acc11 = __builtin_amdgcn_mfma_f32_16x16x32_bf16(afr, bR1, acc11, 0, 0, 0);
    }
    const int orow = r0 + w * 16 + ((lane >> 4) << 2);
    #pragma unroll
    for (int cf = 0; cf < 2; ++cf) {
        const int col = cf * 16 + bcol;
        const float blv = bl2[col], brv = br2[col];
        const f32x4 aL = cf ? acc01 : acc00;
        const f32x4 aR = cf ? acc11 : acc10;
        #pragma unroll
        for (int reg = 0; reg < 4; ++reg) {
            int row = orow + reg;
            if (row < NN) {
                xl2[(size_t)row * DOUT + col] = aL[reg] + blv;
                xr2[(size_t)row * DOUT + col] = aR[reg] + brv;
            }
        }
    }
}

// ---------------- Layer-2 aggregation: 32 nodes/block, 8 lanes/node, 4 ch/lane ----------
__global__ __launch_bounds__(256) void agg2_kernel(
    const float* __restrict__ xl2, const float* __restrict__ xr2,
    const int* __restrict__ row_ptr, const int* __restrict__ sorted_src,
    const float* __restrict__ att2, const float* __restrict__ bias2,
    float* __restrict__ out)
{
    const int t = threadIdx.x;
    const int nsub = t >> 3;              // 0..31
    const int l8 = t & 7;
    const int c0 = l8 * 4;
    const int n = blockIdx.x * 32 + nsub;
    if (n >= NN) return;                  // whole 8-lane group exits uniformly

    const float4 at = *(const float4*)(att2 + c0);
    const float4 xr4 = *(const float4*)(xr2 + (size_t)n * DOUT + c0);
    const int rp = row_ptr[n];
    const int deg = row_ptr[n + 1] - rp;
    const int* sp = sorted_src + rp;

    float l = 0.f, ac0 = 0.f, ac1 = 0.f, ac2 = 0.f, ac3 = 0.f;
    int i = 0;
    for (; i + 2 <= deg; i += 2) {
        unsigned offA = (unsigned)sp[i] * DOUT + c0;
        unsigned offB = (unsigned)sp[i + 1] * DOUT + c0;
        float4 xa = *(const float4*)(xl2 + offA);
        float4 xb = *(const float4*)(xl2 + offB);
        float vA = lrelu(xa.x + xr4.x) * at.x;
        vA = fmaf(lrelu(xa.y + xr4.y), at.y, vA);
        vA = fmaf(lrelu(xa.z + xr4.z), at.z, vA);
        vA = fmaf(lrelu(xa.w + xr4.w), at.w, vA);
        float vB = lrelu(xb.x + xr4.x) * at.x;
        vB = fmaf(lrelu(xb.y + xr4.y), at.y, vB);
        vB = fmaf(lrelu(xb.z + xr4.z), at.z, vB);
        vB = fmaf(lrelu(xb.w + xr4.w), at.w, vB);
        vA += __shfl_xor(vA, 1); vB += __shfl_xor(vB, 1);
        vA += __shfl_xor(vA, 2); vB += __shfl_xor(vB, 2);
        vA += __shfl_xor(vA, 4); vB += __shfl_xor(vB, 4);
        float pA = __expf(vA), pB = __expf(vB);
        l += pA + pB;
        ac0 = fmaf(pA, xa.x, ac0); ac0 = fmaf(pB, xb.x, ac0);
        ac1 = fmaf(pA, xa.y, ac1); ac1 = fmaf(pB, xb.y, ac1);
        ac2 = fmaf(pA, xa.z, ac2); ac2 = fmaf(pB, xb.z, ac2);
        ac3 = fmaf(pA, xa.w, ac3); ac3 = fmaf(pB, xb.w, ac3);
    }
    if (i < deg) {
        unsigned offA = (unsigned)sp[i] * DOUT + c0;
        float4 xa = *(const float4*)(xl2 + offA);
        float vA = lrelu(xa.x + xr4.x) * at.x;
        vA = fmaf(lrelu(xa.y + xr4.y), at.y, vA);
        vA = fmaf(lrelu(xa.z + xr4.z), at.z, vA);
        vA = fmaf(lrelu(xa.w + xr4.w), at.w, vA);
        vA += __shfl_xor(vA, 1);
        vA += __shfl_xor(vA, 2);
        vA += __shfl_xor(vA, 4);
        float pA = __expf(vA);
        l += pA;
        ac0 = fmaf(pA, xa.x, ac0); ac1 = fmaf(pA, xa.y, ac1);
        ac2 = fmaf(pA, xa.z, ac2); ac3 = fmaf(pA, xa.w, ac3);
    }
    const float inv = 1.f / (l + 1e-16f);
    const float4 bi = *(const float4*)(bias2 + c0);
    float o0 = ac0 * inv + bi.x;
    float o1 = ac1 * inv + bi.y;
    float o2 = ac2 * inv + bi.z;
    float o3 = ac3 * inv + bi.w;
    // log_softmax over the node's 32 channels (4 in-lane x 8 lanes)
    float mx = fmaxf(fmaxf(o0, o1), fmaxf(o2, o3));
    mx = fmaxf(mx, __shfl_xor(mx, 1));
    mx = fmaxf(mx, __shfl_xor(mx, 2));
    mx = fmaxf(mx, __shfl_xor(mx, 4));
    float se = __expf(o0 - mx) + __expf(o1 - mx) + __expf(o2 - mx) + __expf(o3 - mx);
    se += __shfl_xor(se, 1);
    se += __shfl_xor(se, 2);
    se += __shfl_xor(se, 4);
    float lse = mx + __logf(se);
    float4 ov; ov.x = o0; ov.y = o1; ov.z = o2; ov.w = o3;
    *(float4*)(out + (size_t)n * DOUT + c0) = ov;
    float4 lv; lv.x = o0 - lse; lv.y = o1 - lse; lv.z = o2 - lse; lv.w = o3 - lse;
    *(float4*)(out + (size_t)(NN + n) * DOUT + c0) = lv;
}

extern "C" void kernel_launch(void* const* d_in, const int* in_sizes, int n_in,
                              void* d_out, int out_size, void* d_ws, size_t ws_size,
                              hipStream_t stream)
{
    const float* x       = (const float*)d_in[0];
    const int*   ei      = (const int*)d_in[1];
    const float* Wl1     = (const float*)d_in[2];
    const float* bl1     = (const float*)d_in[3];
    const float* Wr1     = (const float*)d_in[4];
    const float* br1     = (const float*)d_in[5];
    const float* att1    = (const float*)d_in[6];
    const float* bias1   = (const float*)d_in[7];
    const float* gamma   = (const float*)d_in[8];
    const float* beta    = (const float*)d_in[9];
    const float* prelu_a = (const float*)d_in[10];
    const float* Wl2     = (const float*)d_in[11];
    const float* bl2     = (const float*)d_in[12];
    const float* Wr2     = (const float*)d_in[13];
    const float* br2     = (const float*)d_in[14];
    const float* att2    = (const float*)d_in[15];
    const float* bias2   = (const float*)d_in[16];
    const int* src = ei;
    const int* dst = ei + NE;

    // workspace layout (~98 MB)
    char* w = (char*)d_ws;
    unsigned short* xl1b = (unsigned short*)w;                  // NN*HID bf16 = 32 MB
    unsigned short* xr1b = xl1b + (size_t)NN * HID;             // 32 MB
    unsigned short* h1b  = xr1b + (size_t)NN * HID;             // 32 MB
    char* small = (char*)(h1b + (size_t)NN * HID);              // offset 96,000,000 (16-aligned)
    double* bn_sum = (double*)small;                            // 320 dbl
    double* bn_sq  = bn_sum + HID;                              // 320 dbl
    float* scale   = (float*)(bn_sq + HID);                     // 320 f
    float* shift   = scale + HID;                               // 320 f
    unsigned short* wl2t = (unsigned short*)(shift + HID);      // 10240 bf16
    unsigned short* wr2t = wl2t + HID * DOUT;                   // 10240 bf16
    int* deg       = (int*)(wr2t + HID * DOUT);                 // NN
    int* cursor    = deg + NN;                                  // NN
    int* sorted    = cursor + NN;                               // NE
    int* row_ptr   = sorted + NE;                               // NN+1
    // layer-2 activation buffers reuse the (dead-after-agg1) xl1b region
    float* xl2 = (float*)w;                                     // 6.4 MB
    float* xr2 = (float*)(w + (size_t)NN * DOUT * 4);           // 6.4 MB

    hipMemsetAsync(deg, 0, NN * sizeof(int), stream);
    hipMemsetAsync(bn_sum, 0, 2 * HID * sizeof(double), stream);

    precast_w2<<<(HID * DOUT + 255) / 256, 256, 0, stream>>>(Wl2, Wr2, wl2t, wr2t);
    gemm1_kernel<<<dim3(HID / 32, (NN + 63) / 64), 256, 0, stream>>>(
        x, Wl1, bl1, Wr1, br1, xl1b, xr1b);
    hist_kernel<<<(NE + 255) / 256, 256, 0, stream>>>(dst, deg);
    scan_kernel<<<1, 1024, 0, stream>>>(deg, row_ptr, cursor);
    scatter_kernel<<<(NE + 255) / 256, 256, 0, stream>>>(src, dst, cursor, sorted);
    agg1_kernel<<<NN / 4, 320, 0, stream>>>(xl1b, xr1b, row_ptr, sorted, att1, bias1, h1b);
    bnstats_kernel<<<512, HID, 0, stream>>>(h1b, bn_sum, bn_sq);
    bnfinal_kernel<<<1, HID, 0, stream>>>(bn_sum, bn_sq, gamma, beta, scale, shift);
    gemm2_kernel<<<(NN + 63) / 64, 256, 0, stream>>>(h1b, scale, shift, prelu_a,
        wl2t, wr2t, bl2, br2, xl2, xr2);
    agg2_kernel<<<(NN + 31) / 32, 256, 0, stream>>>(xl2, xr2, row_ptr, sorted, att2, bias2,
        (float*)d_out);
}